// Round 2
// baseline (635.679 us; speedup 1.0000x reference)
//
#include <hip/hip_runtime.h>
#include <math.h>

#define THREADS 256

// ======================= FUSED DIRECT PATH (primary) ========================
// One block per batch row b (4 waves). Each wave keeps the full ro[b] row in
// registers (NCHUNK float4/lane, NCHUNK=E/256), computes invnorm + rowmax from
// those registers (no separate norm kernel), then processes its 1/4 slice of
// the K refs: stream emb[nns[labels[b],k]] (the only per-ref traffic), dot
// against register-resident ro, score -> LDS. One wave then does the
// logsumexp -> loss. Single dispatch, zero workspace.
template <int NCHUNK>
__global__ __launch_bounds__(THREADS) void fused_direct_kernel(
    const float* __restrict__ ro_g,
    const float* __restrict__ emb,
    const int* __restrict__ nns,
    const int* __restrict__ labels,
    const int* __restrict__ nhn_ptr,
    float* __restrict__ loss_out,
    float* __restrict__ acc_out,
    int E, int Knns)
{
    const int b    = blockIdx.x;
    const int tid  = threadIdx.x;
    const int lane = tid & 63;
    const int wave = tid >> 6;
    const int K    = nhn_ptr[0] + 1;

    __shared__ float s_scores[1024];

    // ro[b] -> registers (each wave holds the full row).
    const float4* ro4 = (const float4*)(ro_g + (size_t)b * E);
    float4 r[NCHUNK];
#pragma unroll
    for (int c = 0; c < NCHUNK; ++c) r[c] = ro4[lane + 64 * c];

    // Row sumsq + max from registers (redundant per wave; no LDS, no sync).
    float lsum = 0.f, lmax = -INFINITY;
#pragma unroll
    for (int c = 0; c < NCHUNK; ++c) {
        float4 v = r[c];
        lsum += v.x * v.x + v.y * v.y + v.z * v.z + v.w * v.w;
        lmax = fmaxf(lmax, fmaxf(fmaxf(v.x, v.y), fmaxf(v.z, v.w)));
    }
    for (int m = 32; m; m >>= 1) {
        lsum += __shfl_xor(lsum, m, 64);
        lmax = fmaxf(lmax, __shfl_xor(lmax, m, 64));
    }
    const float inv_norm = 1.0f / sqrtf(lsum);

    // This wave's contiguous k-slice.
    const int Kw = (K + 3) >> 2;
    const int k0 = wave * Kw;
    const int k1 = min(K, k0 + Kw);

    const int* nrow = nns + (size_t)labels[b] * Knns;

    // Ref loop, software-pipelined depth 2: next emb row loads in flight
    // while current row is dotted + reduced.
    int k = k0;
    if (k < k1) {
        float4 e[NCHUNK];
        {
            const float4* e4 = (const float4*)(emb + (size_t)nrow[k] * E);
#pragma unroll
            for (int c = 0; c < NCHUNK; ++c) e[c] = e4[lane + 64 * c];
        }
        while (k < k1) {
            const int kn = k + 1;
            float4 en[NCHUNK];
            if (kn < k1) {
                const float4* f4 = (const float4*)(emb + (size_t)nrow[kn] * E);
#pragma unroll
                for (int c = 0; c < NCHUNK; ++c) en[c] = f4[lane + 64 * c];
            }
            float acc = 0.f;
#pragma unroll
            for (int c = 0; c < NCHUNK; ++c)
                acc += e[c].x * r[c].x + e[c].y * r[c].y +
                       e[c].z * r[c].z + e[c].w * r[c].w;
            for (int m = 32; m; m >>= 1) acc += __shfl_xor(acc, m, 64);
            if (lane == 0) s_scores[k] = acc * inv_norm;
            if (kn < k1) {
#pragma unroll
                for (int c = 0; c < NCHUNK; ++c) e[c] = en[c];
            }
            k = kn;
        }
    }
    __syncthreads();

    // Logsumexp -> loss (wave 0), plus acc from register rowmax.
    if (wave == 0) {
        float m = -INFINITY;
        for (int kk = lane; kk < K; kk += 64) m = fmaxf(m, s_scores[kk]);
        for (int mm = 32; mm; mm >>= 1) m = fmaxf(m, __shfl_xor(m, mm, 64));
        float esum = 0.f;
        for (int kk = lane; kk < K; kk += 64) esum += expf(s_scores[kk] - m);
        for (int mm = 32; mm; mm >>= 1) esum += __shfl_xor(esum, mm, 64);
        if (lane == 0) {
            loss_out[b] = logf(esum) + m - s_scores[0];
            // argmax(ro_norm)==0  <=>  ro[b,0] >= rowmax (first-occurrence ties)
            acc_out[b]  = (ro_g[(size_t)b * E] >= lmax) ? 1.0f : 0.0f;
        }
    }
}

// ======================= FALLBACK PATH (generic shapes) =====================

__global__ __launch_bounds__(THREADS) void build_lists_kernel(
    const int* __restrict__ nns,
    const int* __restrict__ labels,
    const int* __restrict__ nhn_ptr,
    int* __restrict__ head,
    int* __restrict__ next,
    int B, int Knns)
{
    const int rid = blockIdx.x * THREADS + threadIdx.x;
    if (rid >= B * Knns) return;
    const int b = (unsigned)rid / (unsigned)Knns;
    const int k = rid - b * Knns;
    const int K = nhn_ptr[0] + 1;
    if (k >= K) return;
    const int v = nns[(size_t)labels[b] * Knns + k];
    const int old = atomicExch(&head[v], rid);
    next[rid] = old;
}

__global__ __launch_bounds__(THREADS) void row_norm_kernel(
    const float* __restrict__ ro_g,
    float* __restrict__ invn,
    float* __restrict__ acc_out,
    int E)
{
    const int b = blockIdx.x, tid = threadIdx.x, lane = tid & 63, wave = tid >> 6;
    const int E4 = E >> 2;
    __shared__ float s_sum[4], s_max[4];
    const float4* ro4 = (const float4*)(ro_g + (size_t)b * E);
    float lsum = 0.f, lmax = -INFINITY;
    for (int i = tid; i < E4; i += THREADS) {
        float4 v = ro4[i];
        lsum += v.x * v.x + v.y * v.y + v.z * v.z + v.w * v.w;
        lmax = fmaxf(lmax, fmaxf(fmaxf(v.x, v.y), fmaxf(v.z, v.w)));
    }
    for (int m = 32; m; m >>= 1) {
        lsum += __shfl_xor(lsum, m, 64);
        lmax = fmaxf(lmax, __shfl_xor(lmax, m, 64));
    }
    if (lane == 0) { s_sum[wave] = lsum; s_max[wave] = lmax; }
    __syncthreads();
    if (tid == 0) {
        float t = 0.f, mx = -INFINITY;
        for (int w = 0; w < 4; ++w) { t += s_sum[w]; mx = fmaxf(mx, s_max[w]); }
        invn[b] = 1.0f / sqrtf(t);
        acc_out[b] = (ro_g[(size_t)b * E] >= mx) ? 1.0f : 0.0f;
    }
}

__global__ __launch_bounds__(THREADS) void gather_dot_generic(
    const float* __restrict__ emb,
    const float* __restrict__ ro_g,
    const float* __restrict__ invn,
    const int* __restrict__ head,
    const int* __restrict__ next,
    float* __restrict__ scores,
    int V, int E, int Knns)
{
    const int lane = threadIdx.x & 63;
    const int wave = threadIdx.x >> 6;
    const int v = blockIdx.x * 4 + wave;
    if (v >= V) return;
    int i = head[v];
    if (i < 0) return;
    const int E4 = E >> 2;
    const float4* e4 = (const float4*)(emb + (size_t)v * E);
    while (i >= 0) {
        const int inext = next[i];
        const int b = (unsigned)i / (unsigned)Knns;
        const float4* ro4 = (const float4*)(ro_g + (size_t)b * E);
        float acc = 0.f;
        for (int j = lane; j < E4; j += 64) {
            float4 x = ro4[j], e = e4[j];
            acc += x.x * e.x + x.y * e.y + x.z * e.z + x.w * e.w;
        }
        for (int m = 32; m; m >>= 1) acc += __shfl_xor(acc, m, 64);
        if (lane == 0) scores[i] = acc * invn[b];
        i = inext;
    }
}

__global__ __launch_bounds__(THREADS) void loss_kernel(
    const float* __restrict__ scores,
    const int* __restrict__ nhn_ptr,
    float* __restrict__ loss_out,
    int B, int Knns)
{
    const int lane = threadIdx.x & 63;
    const int wave = threadIdx.x >> 6;
    const int b = blockIdx.x * 4 + wave;
    if (b >= B) return;
    const int K = nhn_ptr[0] + 1;
    const float* s = scores + (size_t)b * Knns;
    float m = -INFINITY;
    for (int k = lane; k < K; k += 64) m = fmaxf(m, s[k]);
    for (int mm = 32; mm; mm >>= 1) m = fmaxf(m, __shfl_xor(m, mm, 64));
    float e = 0.f;
    for (int k = lane; k < K; k += 64) e += expf(s[k] - m);
    for (int mm = 32; mm; mm >>= 1) e += __shfl_xor(e, mm, 64);
    if (lane == 0) loss_out[b] = logf(e) + m - s[0];
}

// ============================== launcher ====================================
extern "C" void kernel_launch(void* const* d_in, const int* in_sizes, int n_in,
                              void* d_out, int out_size, void* d_ws, size_t ws_size,
                              hipStream_t stream) {
    const float* ro     = (const float*)d_in[0];
    const float* emb    = (const float*)d_in[1];
    const int*   nns    = (const int*)d_in[2];
    const int*   labels = (const int*)d_in[3];
    const int*   nhn    = (const int*)d_in[4];

    const int B    = in_sizes[3];                 // 2048
    const int E    = in_sizes[0] / B;             // 1024
    const int V    = in_sizes[1] / E;             // 100000
    const int Knns = in_sizes[2] / V;             // 128

    float* loss_out = (float*)d_out;
    float* acc_out  = loss_out + B;

    const int nchunk = (E % 256 == 0) ? (E / 256) : 0;
    const bool direct_ok = (Knns <= 1024) &&
        (nchunk == 1 || nchunk == 2 || nchunk == 4 || nchunk == 8);

    if (direct_ok) {
        switch (nchunk) {
            case 1: fused_direct_kernel<1><<<dim3(B), dim3(THREADS), 0, stream>>>(
                        ro, emb, nns, labels, nhn, loss_out, acc_out, E, Knns); break;
            case 2: fused_direct_kernel<2><<<dim3(B), dim3(THREADS), 0, stream>>>(
                        ro, emb, nns, labels, nhn, loss_out, acc_out, E, Knns); break;
            case 4: fused_direct_kernel<4><<<dim3(B), dim3(THREADS), 0, stream>>>(
                        ro, emb, nns, labels, nhn, loss_out, acc_out, E, Knns); break;
            default: fused_direct_kernel<8><<<dim3(B), dim3(THREADS), 0, stream>>>(
                        ro, emb, nns, labels, nhn, loss_out, acc_out, E, Knns); break;
        }
        return;
    }

    // Generic fallback: inverted linked-list path.
    char* ws = (char*)d_ws;
    auto align = [](size_t x) { return (x + 255) & ~(size_t)255; };
    int*   head   = (int*)ws;                         ws += align((size_t)V * 4);
    int*   next   = (int*)ws;                         ws += align((size_t)B * Knns * 4);
    float* invn   = (float*)ws;                       ws += align((size_t)B * 4);
    float* scores = (float*)ws;

    hipMemsetAsync(head, 0xFF, (size_t)V * sizeof(int), stream);

    const int nrefs = B * Knns;
    build_lists_kernel<<<dim3((nrefs + THREADS - 1) / THREADS), dim3(THREADS), 0, stream>>>(
        nns, labels, nhn, head, next, B, Knns);

    row_norm_kernel<<<dim3(B), dim3(THREADS), 0, stream>>>(ro, invn, acc_out, E);

    const int vblocks = (V + 3) / 4;
    gather_dot_generic<<<dim3(vblocks), dim3(THREADS), 0, stream>>>(
        emb, ro, invn, head, next, scores, V, E, Knns);

    loss_kernel<<<dim3((B + 3) / 4), dim3(THREADS), 0, stream>>>(
        scores, nhn, loss_out, B, Knns);
}

// Round 3
// 606.626 us; speedup vs baseline: 1.0479x; 1.0479x over previous
//
#include <hip/hip_runtime.h>
#include <math.h>

#define THREADS 256

// ---------------- K1+K2 fused: list build + per-row norm/acc ----------------
// Blocks [0, B): one block per batch row -> invn[b], acc_out[b].
// Blocks [B, ...): flat ref ids -> linked-list build (head must be -1 first).
__global__ __launch_bounds__(THREADS) void build_norm_kernel(
    const int* __restrict__ nns,
    const int* __restrict__ labels,
    const int* __restrict__ nhn_ptr,
    int* __restrict__ head,
    int* __restrict__ next,
    const float* __restrict__ ro_g,
    float* __restrict__ invn,
    float* __restrict__ acc_out,
    int B, int Knns, int E)
{
    if ((int)blockIdx.x < B) {
        // ---- norm part ----
        const int b = blockIdx.x, tid = threadIdx.x, lane = tid & 63, wave = tid >> 6;
        const int E4 = E >> 2;
        __shared__ float s_sum[4], s_max[4];
        const float4* ro4 = (const float4*)(ro_g + (size_t)b * E);
        float lsum = 0.f, lmax = -INFINITY;
        for (int i = tid; i < E4; i += THREADS) {
            float4 v = ro4[i];
            lsum += v.x * v.x + v.y * v.y + v.z * v.z + v.w * v.w;
            lmax = fmaxf(lmax, fmaxf(fmaxf(v.x, v.y), fmaxf(v.z, v.w)));
        }
        for (int m = 32; m; m >>= 1) {
            lsum += __shfl_xor(lsum, m, 64);
            lmax = fmaxf(lmax, __shfl_xor(lmax, m, 64));
        }
        if (lane == 0) { s_sum[wave] = lsum; s_max[wave] = lmax; }
        __syncthreads();
        if (tid == 0) {
            float t = 0.f, mx = -INFINITY;
            for (int w = 0; w < 4; ++w) { t += s_sum[w]; mx = fmaxf(mx, s_max[w]); }
            invn[b] = 1.0f / sqrtf(t);
            // argmax(ro_norm)==0  <=>  ro[b,0] >= rowmax (first-occurrence ties)
            acc_out[b] = (ro_g[(size_t)b * E] >= mx) ? 1.0f : 0.0f;
        }
    } else {
        // ---- list-build part ----
        const int rid = ((int)blockIdx.x - B) * THREADS + threadIdx.x;
        if (rid >= B * Knns) return;
        const int b = (unsigned)rid / (unsigned)Knns;
        const int k = rid - b * Knns;
        const int K = nhn_ptr[0] + 1;
        if (k >= K) return;
        const int v = nns[(size_t)labels[b] * Knns + k];
        const int old = atomicExch(&head[v], rid);
        next[rid] = old;
    }
}

// ---------------- K3: inverted gather-dot -----------------------------------
// One wave per vocab row v. emb[v] is read from HBM exactly once into
// registers (NCHUNK float4/lane, NCHUNK=E/256); the chain's ro rows (8 MB
// total working set) come from L2/L3. [Measured-best structure — unchanged.]
template <int NCHUNK>
__global__ __launch_bounds__(THREADS) void gather_dot_kernel(
    const float* __restrict__ emb,
    const float* __restrict__ ro_g,
    const float* __restrict__ invn,
    const int* __restrict__ head,
    const int* __restrict__ next,
    float* __restrict__ scores,
    int V, int E, int Knns)
{
    const int lane = threadIdx.x & 63;
    const int wave = threadIdx.x >> 6;
    const int v = blockIdx.x * 4 + wave;
    if (v >= V) return;
    int i = head[v];
    if (i < 0) return;

    const float4* e4 = (const float4*)(emb + (size_t)v * E);
    float4 r[NCHUNK];
#pragma unroll
    for (int c = 0; c < NCHUNK; ++c) r[c] = e4[lane + 64 * c];

    while (i >= 0) {
        const int inext = next[i];                    // issue chase early
        const int b = (unsigned)i / (unsigned)Knns;
        const float4* ro4 = (const float4*)(ro_g + (size_t)b * E);
        float acc = 0.f;
#pragma unroll
        for (int c = 0; c < NCHUNK; ++c) {
            float4 x = ro4[lane + 64 * c];
            float4 rc = r[c];
            acc += x.x * rc.x + x.y * rc.y + x.z * rc.z + x.w * rc.w;
        }
        for (int m = 32; m; m >>= 1) acc += __shfl_xor(acc, m, 64);
        if (lane == 0) scores[i] = acc * invn[b];
        i = inext;
    }
}

// Generic-E fallback: same inversion, emb re-read per ref (L1-hot).
__global__ __launch_bounds__(THREADS) void gather_dot_generic(
    const float* __restrict__ emb,
    const float* __restrict__ ro_g,
    const float* __restrict__ invn,
    const int* __restrict__ head,
    const int* __restrict__ next,
    float* __restrict__ scores,
    int V, int E, int Knns)
{
    const int lane = threadIdx.x & 63;
    const int wave = threadIdx.x >> 6;
    const int v = blockIdx.x * 4 + wave;
    if (v >= V) return;
    int i = head[v];
    if (i < 0) return;
    const int E4 = E >> 2;
    const float4* e4 = (const float4*)(emb + (size_t)v * E);
    while (i >= 0) {
        const int inext = next[i];
        const int b = (unsigned)i / (unsigned)Knns;
        const float4* ro4 = (const float4*)(ro_g + (size_t)b * E);
        float acc = 0.f;
        for (int j = lane; j < E4; j += 64) {
            float4 x = ro4[j], e = e4[j];
            acc += x.x * e.x + x.y * e.y + x.z * e.z + x.w * e.w;
        }
        for (int m = 32; m; m >>= 1) acc += __shfl_xor(acc, m, 64);
        if (lane == 0) scores[i] = acc * invn[b];
        i = inext;
    }
}

// ---------------- K4: per-row logsumexp -> loss -----------------------------
__global__ __launch_bounds__(THREADS) void loss_kernel(
    const float* __restrict__ scores,
    const int* __restrict__ nhn_ptr,
    float* __restrict__ loss_out,
    int B, int Knns)
{
    const int lane = threadIdx.x & 63;
    const int wave = threadIdx.x >> 6;
    const int b = blockIdx.x * 4 + wave;
    if (b >= B) return;
    const int K = nhn_ptr[0] + 1;
    const float* s = scores + (size_t)b * Knns;
    float m = -INFINITY;
    for (int k = lane; k < K; k += 64) m = fmaxf(m, s[k]);
    for (int mm = 32; mm; mm >>= 1) m = fmaxf(m, __shfl_xor(m, mm, 64));
    float e = 0.f;
    for (int k = lane; k < K; k += 64) e += expf(s[k] - m);
    for (int mm = 32; mm; mm >>= 1) e += __shfl_xor(e, mm, 64);
    if (lane == 0) loss_out[b] = logf(e) + m - s[0];
}

extern "C" void kernel_launch(void* const* d_in, const int* in_sizes, int n_in,
                              void* d_out, int out_size, void* d_ws, size_t ws_size,
                              hipStream_t stream) {
    const float* ro     = (const float*)d_in[0];
    const float* emb    = (const float*)d_in[1];
    const int*   nns    = (const int*)d_in[2];
    const int*   labels = (const int*)d_in[3];
    const int*   nhn    = (const int*)d_in[4];

    const int B    = in_sizes[3];                 // 2048
    const int E    = in_sizes[0] / B;             // 1024
    const int V    = in_sizes[1] / E;             // 100000
    const int Knns = in_sizes[2] / V;             // 128

    float* loss_out = (float*)d_out;
    float* acc_out  = loss_out + B;

    // Workspace layout (256B-aligned slices).
    char* ws = (char*)d_ws;
    auto align = [](size_t x) { return (x + 255) & ~(size_t)255; };
    int*   head   = (int*)ws;                         ws += align((size_t)V * 4);
    int*   next   = (int*)ws;                         ws += align((size_t)B * Knns * 4);
    float* invn   = (float*)ws;                       ws += align((size_t)B * 4);
    float* scores = (float*)ws;

    hipMemsetAsync(head, 0xFF, (size_t)V * sizeof(int), stream);   // head = -1

    // Fused K1+K2: blocks [0,B) do norm/acc, blocks [B, B+buildBlocks) build
    // the per-vocab linked lists. Independent work, one dispatch.
    const int nrefs = B * Knns;
    const int buildBlocks = (nrefs + THREADS - 1) / THREADS;
    build_norm_kernel<<<dim3(B + buildBlocks), dim3(THREADS), 0, stream>>>(
        nns, labels, nhn, head, next, ro, invn, acc_out, B, Knns, E);

    const int vblocks = (V + 3) / 4;
    const int nchunk = (E % 256 == 0) ? (E / 256) : 0;
    switch (nchunk) {
        case 1: gather_dot_kernel<1><<<dim3(vblocks), dim3(THREADS), 0, stream>>>(
                    emb, ro, invn, head, next, scores, V, E, Knns); break;
        case 2: gather_dot_kernel<2><<<dim3(vblocks), dim3(THREADS), 0, stream>>>(
                    emb, ro, invn, head, next, scores, V, E, Knns); break;
        case 4: gather_dot_kernel<4><<<dim3(vblocks), dim3(THREADS), 0, stream>>>(
                    emb, ro, invn, head, next, scores, V, E, Knns); break;
        case 8: gather_dot_kernel<8><<<dim3(vblocks), dim3(THREADS), 0, stream>>>(
                    emb, ro, invn, head, next, scores, V, E, Knns); break;
        default: gather_dot_generic<<<dim3(vblocks), dim3(THREADS), 0, stream>>>(
                    emb, ro, invn, head, next, scores, V, E, Knns);
    }

    loss_kernel<<<dim3((B + 3) / 4), dim3(THREADS), 0, stream>>>(
        scores, nhn, loss_out, B, Knns);
}